// Round 1
// baseline (958.105 us; speedup 1.0000x reference)
//
#include <hip/hip_runtime.h>
#include <hip/hip_bf16.h>
#include <math.h>

// ---------------------------------------------------------------------------
// BottleneckSparseAttention2D: fully fused transformer block.
// One workgroup (512 thr = 8 waves) per 64-token window; 8192 windows.
// Residual x2 lives in registers (C-layout, wave w owns cols w*16..w*16+15).
// All GEMMs: mfma_f32_16x16x32_bf16, A from swizzled LDS, B from packed global.
// Verified layouts (guide §3): A[m=lane&15][k=quad*8+j], B[k=quad*8+j][n=lane&15],
//                              D[row=quad*4+reg][col=lane&15].
// ---------------------------------------------------------------------------

typedef __bf16 bf16;
typedef __bf16 bf16x8 __attribute__((ext_vector_type(8)));
typedef float  f32x4  __attribute__((ext_vector_type(4)));

#define MFMA16(a, b, c) __builtin_amdgcn_mfma_f32_16x16x32_bf16((a), (b), (c), 0, 0, 0)

// packed-weight element offsets inside d_ws (bf16 elements)
constexpr int OFF_PRE  = 0;       // w_pre  64x128 : KT=2, NT=8  -> 16 tiles
constexpr int OFF_QKV  = 8192;    // w_qkv 128x384 : KT=4, NT=24 -> 96 tiles
constexpr int OFF_PROJ = 57344;   // w_proj128x128 : KT=4, NT=8  -> 32 tiles
constexpr int OFF_M1   = 73728;   // w_m1  128x256 : KT=4, NT=16 -> 64 tiles
constexpr int OFF_M2   = 106496;  // w_m2  256x128 : KT=8, NT=8  -> 64 tiles
constexpr int OFF_POST = 139264;  // w_post128x64  : KT=4, NT=4  -> 16 tiles
// total 147456 bf16 = 288 KB in d_ws

// XOR-swizzled row-major layout: 16B chunks XOR'd with row -> conflict-free-ish
// ds_read_b128 without padding (keeps total LDS at exactly 64 KB).
template <int W>
__device__ __forceinline__ int swz(int row, int col) {
    constexpr int CH = W >> 3;
    constexpr int M  = (CH - 1) < 15 ? (CH - 1) : 15;
    const int c = (col >> 3) ^ (row & M);
    return row * W + c * 8 + (col & 7);
}

__device__ __forceinline__ bf16x8 zero8() {
    bf16x8 z;
#pragma unroll
    for (int j = 0; j < 8; ++j) z[j] = (bf16)0.0f;
    return z;
}

// ---------------------------------------------------------------------------
// Weight packer: fp32 W[K][N] -> B-fragment tiles. Tile (nt,kt) holds, for lane
// l, elements W[kt*32 + (l>>4)*8 + j][nt*16 + (l&15)] at dst[(tile*64+l)*8+j].
// Rerun every launch (d_ws is re-poisoned by the harness).
// ---------------------------------------------------------------------------
__global__ void pack_w(const float* __restrict__ wsrc, bf16* __restrict__ dst,
                       int KT, int Ncol) {
    const int lane = threadIdx.x;
    const int tile = blockIdx.x;
    const int nt = tile / KT, kt = tile - nt * KT;
    const int n  = nt * 16 + (lane & 15);
    const int k0 = kt * 32 + (lane >> 4) * 8;
    bf16x8 v;
#pragma unroll
    for (int j = 0; j < 8; ++j) v[j] = (bf16)wsrc[(k0 + j) * Ncol + n];
    *(bf16x8*)(dst + ((long)(tile * 64 + lane)) * 8) = v;
}

// LayerNorm over 128 channels: 8 lanes per row, shuffle-reduce, bf16 out.
__device__ __forceinline__ void ln_rows(const bf16* __restrict__ in,
                                        bf16* __restrict__ outb,
                                        const float* __restrict__ g,
                                        const float* __restrict__ b, int tid) {
    const int row = tid >> 3, sub = tid & 7;
    bf16x8 c0 = *(const bf16x8*)(in + swz<128>(row, sub * 16));
    bf16x8 c1 = *(const bf16x8*)(in + swz<128>(row, sub * 16 + 8));
    float v[16];
#pragma unroll
    for (int j = 0; j < 8; ++j) { v[j] = (float)c0[j]; v[8 + j] = (float)c1[j]; }
    float s = 0.f, ss = 0.f;
#pragma unroll
    for (int j = 0; j < 16; ++j) { s += v[j]; ss += v[j] * v[j]; }
#pragma unroll
    for (int m = 1; m <= 4; m <<= 1) {
        s += __shfl_xor(s, m);
        ss += __shfl_xor(ss, m);
    }
    const float mu   = s * (1.0f / 128.0f);
    const float rstd = rsqrtf(ss * (1.0f / 128.0f) - mu * mu + 1e-5f);
    bf16x8 o0, o1;
#pragma unroll
    for (int j = 0; j < 8; ++j) {
        o0[j] = (bf16)((v[j] - mu) * rstd * g[sub * 16 + j] + b[sub * 16 + j]);
        o1[j] = (bf16)((v[8 + j] - mu) * rstd * g[sub * 16 + 8 + j] + b[sub * 16 + 8 + j]);
    }
    *(bf16x8*)(outb + swz<128>(row, sub * 16)) = o0;
    *(bf16x8*)(outb + swz<128>(row, sub * 16 + 8)) = o1;
}

__global__ __launch_bounds__(512, 4)
void fused_block_kernel(const float* __restrict__ feats,
                        const bf16* __restrict__ wp,
                        const float* __restrict__ b_pre,
                        const float* __restrict__ g1, const float* __restrict__ b1,
                        const float* __restrict__ b_qkv,
                        const float* __restrict__ b_proj,
                        const float* __restrict__ g2, const float* __restrict__ b2,
                        const float* __restrict__ b_m1,
                        const float* __restrict__ b_m2,
                        const float* __restrict__ b_post,
                        float* __restrict__ out) {
    // Exactly 64 KB static LDS, four 16 KB regions, time-multiplexed:
    //  R1: n1 -> O -> n2 -> x2_bf16(post input)
    //  R2: feats(bf16) -> Q
    //  R3: x2_bf16(LN inputs) -> K      R4: V^T per head
    //  R3..R4 combined: MLP hidden (64x256)
    __shared__ __align__(16) bf16 R1[64 * 128];
    __shared__ __align__(16) bf16 R2[64 * 128];
    __shared__ __align__(16) bf16 R34[64 * 256];
    bf16* const R3 = R34;
    bf16* const R4 = R34 + 64 * 128;

    const int tid  = threadIdx.x;
    const int w    = tid >> 6;   // wave 0..7 == head / col-tile owner
    const int lane = tid & 63;
    const int q    = lane >> 4;  // quad
    const int l15  = lane & 15;
    const long base = (long)blockIdx.x * 64;
    const f32x4 fzero = {0.f, 0.f, 0.f, 0.f};

    // -------- stage 0: feats (64x64 fp32) -> R2 bf16, swizzled --------------
    {
        const int row = tid >> 3, ch = tid & 7;
        const float* src = feats + (base + row) * 64 + ch * 8;
        float4 a = *(const float4*)src;
        float4 b = *(const float4*)(src + 4);
        bf16x8 v;
        v[0] = (bf16)a.x; v[1] = (bf16)a.y; v[2] = (bf16)a.z; v[3] = (bf16)a.w;
        v[4] = (bf16)b.x; v[5] = (bf16)b.y; v[6] = (bf16)b.z; v[7] = (bf16)b.w;
        *(bf16x8*)(R2 + swz<64>(row, ch * 8)) = v;
    }
    __syncthreads();

    f32x4 x2[4];  // residual stream: rows rt*16+q*4+r, col w*16+l15 (fp32, regs)

    // -------- stage 1: x2 = feats @ w_pre + b_pre ---------------------------
    {
        f32x4 acc[4];
#pragma unroll
        for (int rt = 0; rt < 4; ++rt) acc[rt] = fzero;
#pragma unroll
        for (int ks = 0; ks < 2; ++ks) {
            bf16x8 bfr = *(const bf16x8*)(wp + OFF_PRE + ((w * 2 + ks) * 64 + lane) * 8);
#pragma unroll
            for (int rt = 0; rt < 4; ++rt) {
                bf16x8 afr = *(const bf16x8*)(R2 + swz<64>(rt * 16 + l15, ks * 32 + q * 8));
                acc[rt] = MFMA16(afr, bfr, acc[rt]);
            }
        }
        const float bias = b_pre[w * 16 + l15];
#pragma unroll
        for (int rt = 0; rt < 4; ++rt)
#pragma unroll
            for (int r = 0; r < 4; ++r) {
                x2[rt][r] = acc[rt][r] + bias;
                R3[swz<128>(rt * 16 + q * 4 + r, w * 16 + l15)] = (bf16)x2[rt][r];
            }
    }
    __syncthreads();

    // -------- stage 2: n1 = LN(x2)*g1+b1 -> R1 ------------------------------
    ln_rows(R3, R1, g1, b1, tid);
    __syncthreads();

    // -------- stage 3: qkv = n1 @ w_qkv + b_qkv -----------------------------
    // wave w produces head w's Q (->R2 row-major), K (->R3 row-major),
    // V (->R4 transposed per head).
    {
        bf16x8 A[4][4];
#pragma unroll
        for (int ks = 0; ks < 4; ++ks)
#pragma unroll
            for (int rt = 0; rt < 4; ++rt)
                A[ks][rt] = *(const bf16x8*)(R1 + swz<128>(rt * 16 + l15, ks * 32 + q * 8));
#pragma unroll
        for (int part = 0; part < 3; ++part) {
            const int nt = part * 8 + w;
            f32x4 acc[4];
#pragma unroll
            for (int rt = 0; rt < 4; ++rt) acc[rt] = fzero;
#pragma unroll
            for (int ks = 0; ks < 4; ++ks) {
                bf16x8 bfr = *(const bf16x8*)(wp + OFF_QKV + ((nt * 4 + ks) * 64 + lane) * 8);
#pragma unroll
                for (int rt = 0; rt < 4; ++rt) acc[rt] = MFMA16(A[ks][rt], bfr, acc[rt]);
            }
            const float bias = b_qkv[nt * 16 + l15];
            if (part == 0) {
#pragma unroll
                for (int rt = 0; rt < 4; ++rt)
#pragma unroll
                    for (int r = 0; r < 4; ++r)
                        R2[swz<128>(rt * 16 + q * 4 + r, w * 16 + l15)] = (bf16)(acc[rt][r] + bias);
            } else if (part == 1) {
#pragma unroll
                for (int rt = 0; rt < 4; ++rt)
#pragma unroll
                    for (int r = 0; r < 4; ++r)
                        R3[swz<128>(rt * 16 + q * 4 + r, w * 16 + l15)] = (bf16)(acc[rt][r] + bias);
            } else {
#pragma unroll
                for (int rt = 0; rt < 4; ++rt)
#pragma unroll
                    for (int r = 0; r < 4; ++r) {
                        const int tok = rt * 16 + q * 4 + r;
                        R4[w * 1024 + swz<64>(l15, tok)] = (bf16)(acc[rt][r] + bias);
                    }
            }
        }
    }
    __syncthreads();

    // -------- stage 4: attention (wave w = head w), S^T = K.Q^T trick -------
    {
        const int colA = w * 16 + (q & 1) * 8;  // quads>=2 clamped + zeroed (K-pad)
        const bool hi = (q >= 2);
        const bf16x8 z8 = zero8();
        bf16x8 Kf[4];
#pragma unroll
        for (int kt = 0; kt < 4; ++kt) {
            bf16x8 t = *(const bf16x8*)(R3 + swz<128>(kt * 16 + l15, colA));
            Kf[kt] = hi ? z8 : t;
        }
#pragma unroll
        for (int qt = 0; qt < 4; ++qt) {
            bf16x8 t = *(const bf16x8*)(R2 + swz<128>(qt * 16 + l15, colA));
            bf16x8 Qf = hi ? z8 : t;
            f32x4 S[4];
#pragma unroll
            for (int kt = 0; kt < 4; ++kt) S[kt] = MFMA16(Kf[kt], Qf, fzero);
            // softmax over ktok (rows of S^T) for fixed column qtok=qt*16+l15
            float P[4][4];
            float mx = -1e30f;
#pragma unroll
            for (int kt = 0; kt < 4; ++kt)
#pragma unroll
                for (int r = 0; r < 4; ++r) {
                    const float sv = S[kt][r] * 0.25f;  // HD^-0.5
                    P[kt][r] = sv;
                    mx = fmaxf(mx, sv);
                }
            mx = fmaxf(mx, __shfl_xor(mx, 16));
            mx = fmaxf(mx, __shfl_xor(mx, 32));
            float lsum = 0.f;
#pragma unroll
            for (int kt = 0; kt < 4; ++kt)
#pragma unroll
                for (int r = 0; r < 4; ++r) {
                    const float e = exp2f((P[kt][r] - mx) * 1.4426950408889634f);
                    P[kt][r] = e;
                    lsum += e;
                }
            lsum += __shfl_xor(lsum, 16);
            lsum += __shfl_xor(lsum, 32);
            const float inv = 1.0f / lsum;
#pragma unroll
            for (int kt = 0; kt < 4; ++kt)
#pragma unroll
                for (int r = 0; r < 4; ++r) P[kt][r] *= inv;
            // O^T = V^T @ P^T ; P^T B-frags built in-register via shuffles
            f32x4 O = fzero;
#pragma unroll
            for (int ks = 0; ks < 2; ++ks) {
                bf16x8 Bf;
#pragma unroll
                for (int j = 0; j < 8; ++j) {
                    const int src = (((q & 1) * 2 + (j >> 2)) << 4) + l15;
                    const float v0 = __shfl(P[ks * 2][j & 3], src);
                    const float v1 = __shfl(P[ks * 2 + 1][j & 3], src);
                    Bf[j] = (bf16)((q >> 1) ? v1 : v0);
                }
                bf16x8 Af = *(const bf16x8*)(R4 + w * 1024 + swz<64>(l15, ks * 32 + q * 8));
                O = MFMA16(Af, Bf, O);
            }
#pragma unroll
            for (int r = 0; r < 4; ++r)
                R1[swz<128>(qt * 16 + l15, w * 16 + q * 4 + r)] = (bf16)O[r];
        }
    }
    __syncthreads();

    // -------- stage 5: x2 += O @ w_proj + b_proj; x2_bf16 -> R3 -------------
    {
        f32x4 acc[4];
#pragma unroll
        for (int rt = 0; rt < 4; ++rt) acc[rt] = fzero;
#pragma unroll
        for (int ks = 0; ks < 4; ++ks) {
            bf16x8 bfr = *(const bf16x8*)(wp + OFF_PROJ + ((w * 4 + ks) * 64 + lane) * 8);
#pragma unroll
            for (int rt = 0; rt < 4; ++rt) {
                bf16x8 afr = *(const bf16x8*)(R1 + swz<128>(rt * 16 + l15, ks * 32 + q * 8));
                acc[rt] = MFMA16(afr, bfr, acc[rt]);
            }
        }
        const float bias = b_proj[w * 16 + l15];
#pragma unroll
        for (int rt = 0; rt < 4; ++rt)
#pragma unroll
            for (int r = 0; r < 4; ++r) {
                x2[rt][r] += acc[rt][r] + bias;
                R3[swz<128>(rt * 16 + q * 4 + r, w * 16 + l15)] = (bf16)x2[rt][r];
            }
    }
    __syncthreads();

    // -------- stage 6: n2 = LN(x2)*g2+b2 -> R1 ------------------------------
    ln_rows(R3, R1, g2, b2, tid);
    __syncthreads();

    // -------- stage 7: m = gelu(n2 @ w_m1 + b_m1) -> R34 (64x256) -----------
    {
        bf16x8 A[4][4];
#pragma unroll
        for (int ks = 0; ks < 4; ++ks)
#pragma unroll
            for (int rt = 0; rt < 4; ++rt)
                A[ks][rt] = *(const bf16x8*)(R1 + swz<128>(rt * 16 + l15, ks * 32 + q * 8));
#pragma unroll
        for (int half = 0; half < 2; ++half) {
            const int nt = w * 2 + half;
            f32x4 acc[4];
#pragma unroll
            for (int rt = 0; rt < 4; ++rt) acc[rt] = fzero;
#pragma unroll
            for (int ks = 0; ks < 4; ++ks) {
                bf16x8 bfr = *(const bf16x8*)(wp + OFF_M1 + ((nt * 4 + ks) * 64 + lane) * 8);
#pragma unroll
                for (int rt = 0; rt < 4; ++rt) acc[rt] = MFMA16(A[ks][rt], bfr, acc[rt]);
            }
            const float bias = b_m1[nt * 16 + l15];
#pragma unroll
            for (int rt = 0; rt < 4; ++rt)
#pragma unroll
                for (int r = 0; r < 4; ++r) {
                    const float xv = acc[rt][r] + bias;
                    const float gl = 0.5f * xv * (1.0f + erff(xv * 0.70710678118654752f));
                    R34[swz<256>(rt * 16 + q * 4 + r, nt * 16 + l15)] = (bf16)gl;
                }
        }
    }
    __syncthreads();

    // -------- stage 8: x2 += m @ w_m2 + b_m2; x2_bf16 -> R1 -----------------
    {
        f32x4 acc[4];
#pragma unroll
        for (int rt = 0; rt < 4; ++rt) acc[rt] = fzero;
#pragma unroll
        for (int ks = 0; ks < 8; ++ks) {
            bf16x8 bfr = *(const bf16x8*)(wp + OFF_M2 + ((w * 8 + ks) * 64 + lane) * 8);
#pragma unroll
            for (int rt = 0; rt < 4; ++rt) {
                bf16x8 afr = *(const bf16x8*)(R34 + swz<256>(rt * 16 + l15, ks * 32 + q * 8));
                acc[rt] = MFMA16(afr, bfr, acc[rt]);
            }
        }
        const float bias = b_m2[w * 16 + l15];
#pragma unroll
        for (int rt = 0; rt < 4; ++rt)
#pragma unroll
            for (int r = 0; r < 4; ++r) {
                x2[rt][r] += acc[rt][r] + bias;
                R1[swz<128>(rt * 16 + q * 4 + r, w * 16 + l15)] = (bf16)x2[rt][r];
            }
    }
    __syncthreads();

    // -------- stage 9: out = x2 @ w_post + b_post (fp32 to global) ----------
    {
        const int ct  = w >> 1;
        const int rt0 = (w & 1) * 2;
        f32x4 acc[2];
#pragma unroll
        for (int rr = 0; rr < 2; ++rr) acc[rr] = fzero;
#pragma unroll
        for (int ks = 0; ks < 4; ++ks) {
            bf16x8 bfr = *(const bf16x8*)(wp + OFF_POST + ((ct * 4 + ks) * 64 + lane) * 8);
#pragma unroll
            for (int rr = 0; rr < 2; ++rr) {
                bf16x8 afr = *(const bf16x8*)(R1 + swz<128>((rt0 + rr) * 16 + l15, ks * 32 + q * 8));
                acc[rr] = MFMA16(afr, bfr, acc[rr]);
            }
        }
        const float bias = b_post[ct * 16 + l15];
#pragma unroll
        for (int rr = 0; rr < 2; ++rr)
#pragma unroll
            for (int r = 0; r < 4; ++r)
                out[(base + (rt0 + rr) * 16 + q * 4 + r) * 64 + ct * 16 + l15] = acc[rr][r] + bias;
    }
}

extern "C" void kernel_launch(void* const* d_in, const int* in_sizes, int n_in,
                              void* d_out, int out_size, void* d_ws, size_t ws_size,
                              hipStream_t stream) {
    const float* feats  = (const float*)d_in[0];
    const float* w_pre  = (const float*)d_in[1];
    const float* b_pre  = (const float*)d_in[2];
    const float* g1     = (const float*)d_in[3];
    const float* b1     = (const float*)d_in[4];
    const float* w_qkv  = (const float*)d_in[5];
    const float* b_qkv  = (const float*)d_in[6];
    const float* w_proj = (const float*)d_in[7];
    const float* b_proj = (const float*)d_in[8];
    const float* g2     = (const float*)d_in[9];
    const float* b2     = (const float*)d_in[10];
    const float* w_m1   = (const float*)d_in[11];
    const float* b_m1   = (const float*)d_in[12];
    const float* w_m2   = (const float*)d_in[13];
    const float* b_m2   = (const float*)d_in[14];
    const float* w_post = (const float*)d_in[15];
    const float* b_post = (const float*)d_in[16];

    bf16* wp = (bf16*)d_ws;  // 288 KB of packed bf16 B-fragments

    pack_w<<<16, 64, 0, stream>>>(w_pre,  wp + OFF_PRE,  2, 128);
    pack_w<<<96, 64, 0, stream>>>(w_qkv,  wp + OFF_QKV,  4, 384);
    pack_w<<<32, 64, 0, stream>>>(w_proj, wp + OFF_PROJ, 4, 128);
    pack_w<<<64, 64, 0, stream>>>(w_m1,   wp + OFF_M1,   4, 256);
    pack_w<<<64, 64, 0, stream>>>(w_m2,   wp + OFF_M2,   8, 128);
    pack_w<<<16, 64, 0, stream>>>(w_post, wp + OFF_POST, 4, 64);

    fused_block_kernel<<<8192, 512, 0, stream>>>(
        feats, wp, b_pre, g1, b1, b_qkv, b_proj, g2, b2, b_m1, b_m2, b_post,
        (float*)d_out);
}

// Round 3
// 636.747 us; speedup vs baseline: 1.5047x; 1.5047x over previous
//
#include <hip/hip_runtime.h>
#include <hip/hip_bf16.h>
#include <math.h>

// ---------------------------------------------------------------------------
// Fully fused transformer block, TRANSPOSED-GEMM formulation.
// One workgroup (512 thr = 8 waves) per 64-token window; 8192 windows.
// Every GEMM computes Z^T = W^T·X^T:  A-frag = W^T (packed, same packing as a
// B-frag of W), B-frag = X^T (bit-identical read pattern to an A-frag of X from
// row-major [token][channel] LDS). D then holds 4 consecutive CHANNELS of one
// token per lane -> all LDS C-writes are ds_write_b64, out-store is dwordx4.
// Layouts (guide §3, HW-verified): A[m=lane&15][k=quad*8+j],
// B[k=quad*8+j][n=lane&15], D[row=quad*4+reg][col=lane&15].
// ---------------------------------------------------------------------------

typedef __bf16 bf16;
typedef __bf16 bf16x8 __attribute__((ext_vector_type(8)));
typedef __bf16 bf16x4 __attribute__((ext_vector_type(4)));
typedef float  f32x4  __attribute__((ext_vector_type(4)));

#define MFMA16(a, b, c) __builtin_amdgcn_mfma_f32_16x16x32_bf16((a), (b), (c), 0, 0, 0)

// packed-weight element offsets inside d_ws (bf16 elements)
constexpr int OFF_PRE  = 0;       // w_pre  64x128 : KT=2, MT=8  -> 16 tiles
constexpr int OFF_QKV  = 8192;    // w_qkv 128x384 : KT=4, MT=24 -> 96 tiles
constexpr int OFF_PROJ = 57344;   // w_proj128x128 : KT=4, MT=8  -> 32 tiles
constexpr int OFF_M1   = 73728;   // w_m1  128x256 : KT=4, MT=16 -> 64 tiles
constexpr int OFF_M2   = 106496;  // w_m2  256x128 : KT=8, MT=8  -> 64 tiles
constexpr int OFF_POST = 139264;  // w_post128x64  : KT=4, MT=4  -> 16 tiles
// total 147456 bf16 = 288 KB in d_ws

// XOR-swizzled row-major layout (16B chunks XOR row) -> conflict-light
// ds_read_b128 / ds_write_b64 without padding; total LDS stays 64 KB.
template <int W>
__device__ __forceinline__ int swz(int row, int col) {
    constexpr int CH = W >> 3;
    constexpr int M  = (CH - 1) < 15 ? (CH - 1) : 15;
    const int c = (col >> 3) ^ (row & M);
    return row * W + c * 8 + (col & 7);
}

__device__ __forceinline__ bf16x8 zero8() {
    bf16x8 z;
#pragma unroll
    for (int j = 0; j < 8; ++j) z[j] = (bf16)0.0f;
    return z;
}

// store 4 fp32 as 4 consecutive bf16 (8B). col base is 4-aligned -> stays
// inside one 8-elem swizzle chunk -> single ds_write_b64.
__device__ __forceinline__ void st4(bf16* p, const f32x4 v) {
    bf16x4 o;
#pragma unroll
    for (int r = 0; r < 4; ++r) o[r] = (bf16)v[r];
    *(bf16x4*)p = o;
}

// fast gelu: x * sigmoid(2u), u = 0.79788456(x + 0.044715 x^3)
__device__ __forceinline__ float gelu_f(float x) {
    const float u = 0.79788456f * x * (1.0f + 0.044715f * x * x);
    const float e = __builtin_amdgcn_exp2f(u * 2.8853900817779268f);  // e^(2u)
    return x - x * __builtin_amdgcn_rcpf(e + 1.0f);  // robust at e->inf
}

// ---------------------------------------------------------------------------
// Weight packer: fp32 W[K][N] -> A-frag tiles of W^T (== B-frag tiles of W).
// Tile (mt,kt): lane l, frag[j] = W[kt*32 + (l>>4)*8 + j][mt*16 + (l&15)].
// All six weights in ONE kernel (288 blocks) to avoid 6 launch latencies.
// ---------------------------------------------------------------------------
__global__ void pack_all(const float* __restrict__ w_pre,
                         const float* __restrict__ w_qkv,
                         const float* __restrict__ w_proj,
                         const float* __restrict__ w_m1,
                         const float* __restrict__ w_m2,
                         const float* __restrict__ w_post,
                         bf16* __restrict__ dst) {
    const int t = blockIdx.x;
    const float* src;
    int Ncol, KT, off, t0;
    if (t < 16)       { src = w_pre;  Ncol = 128; KT = 2; off = OFF_PRE;  t0 = 0; }
    else if (t < 112) { src = w_qkv;  Ncol = 384; KT = 4; off = OFF_QKV;  t0 = 16; }
    else if (t < 144) { src = w_proj; Ncol = 128; KT = 4; off = OFF_PROJ; t0 = 112; }
    else if (t < 208) { src = w_m1;   Ncol = 256; KT = 4; off = OFF_M1;   t0 = 144; }
    else if (t < 272) { src = w_m2;   Ncol = 128; KT = 8; off = OFF_M2;   t0 = 208; }
    else              { src = w_post; Ncol = 64;  KT = 4; off = OFF_POST; t0 = 272; }
    const int tile = t - t0;
    const int lane = threadIdx.x;
    const int mt = tile / KT, kt = tile - mt * KT;
    const int n  = mt * 16 + (lane & 15);
    const int k0 = kt * 32 + (lane >> 4) * 8;
    bf16x8 v;
#pragma unroll
    for (int j = 0; j < 8; ++j) v[j] = (bf16)src[(k0 + j) * Ncol + n];
    // NOTE: destination MUST include the per-weight region offset `off`
    // (round-2 bug: omitted -> all weights overwrote region 0).
    *(bf16x8*)(dst + off + ((long)(tile * 64 + lane)) * 8) = v;
}

// LayerNorm over 128 channels: 8 lanes per row, shuffle-reduce, bf16 out.
__device__ __forceinline__ void ln_rows(const bf16* __restrict__ in,
                                        bf16* __restrict__ outb,
                                        const float* __restrict__ g,
                                        const float* __restrict__ b, int tid) {
    const int row = tid >> 3, sub = tid & 7;
    bf16x8 c0 = *(const bf16x8*)(in + swz<128>(row, sub * 16));
    bf16x8 c1 = *(const bf16x8*)(in + swz<128>(row, sub * 16 + 8));
    float v[16];
#pragma unroll
    for (int j = 0; j < 8; ++j) { v[j] = (float)c0[j]; v[8 + j] = (float)c1[j]; }
    float s = 0.f, ss = 0.f;
#pragma unroll
    for (int j = 0; j < 16; ++j) { s += v[j]; ss += v[j] * v[j]; }
#pragma unroll
    for (int m = 1; m <= 4; m <<= 1) {
        s += __shfl_xor(s, m);
        ss += __shfl_xor(ss, m);
    }
    const float mu   = s * (1.0f / 128.0f);
    const float rstd = __builtin_amdgcn_rsqf(ss * (1.0f / 128.0f) - mu * mu + 1e-5f);
    bf16x8 o0, o1;
#pragma unroll
    for (int j = 0; j < 8; ++j) {
        o0[j] = (bf16)((v[j] - mu) * rstd * g[sub * 16 + j] + b[sub * 16 + j]);
        o1[j] = (bf16)((v[8 + j] - mu) * rstd * g[sub * 16 + 8 + j] + b[sub * 16 + 8 + j]);
    }
    *(bf16x8*)(outb + swz<128>(row, sub * 16)) = o0;
    *(bf16x8*)(outb + swz<128>(row, sub * 16 + 8)) = o1;
}

__global__ __launch_bounds__(512, 4)
void fused_block_kernel(const float* __restrict__ feats,
                        const bf16* __restrict__ wp,
                        const float* __restrict__ b_pre,
                        const float* __restrict__ g1, const float* __restrict__ b1,
                        const float* __restrict__ b_qkv,
                        const float* __restrict__ b_proj,
                        const float* __restrict__ g2, const float* __restrict__ b2,
                        const float* __restrict__ b_m1,
                        const float* __restrict__ b_m2,
                        const float* __restrict__ b_post,
                        float* __restrict__ out) {
    // 64 KB static LDS, four 16 KB regions, time-multiplexed:
    //  R1: n1 -> O -> n2 -> x2_bf16(post input)
    //  R2: feats(bf16) -> Q
    //  R3: x2_bf16(LN1 in) -> K -> x2_bf16(LN2 in)   R4: V^T per head
    //  R3..R4 combined: MLP hidden (64x256)
    __shared__ __align__(16) bf16 R1[64 * 128];
    __shared__ __align__(16) bf16 R2[64 * 128];
    __shared__ __align__(16) bf16 R34[64 * 256];
    bf16* const R3 = R34;
    bf16* const R4 = R34 + 64 * 128;

    const int tid  = threadIdx.x;
    const int w    = tid >> 6;   // wave 0..7 == head / out-channel-tile owner
    const int lane = tid & 63;
    const int q    = lane >> 4;  // quad
    const int l15  = lane & 15;
    const long base = (long)blockIdx.x * 64;
    const f32x4 fzero = {0.f, 0.f, 0.f, 0.f};

    // -------- stage 0: feats (64x64 fp32) -> R2 bf16, swizzled --------------
    {
        const int row = tid >> 3, ch = tid & 7;
        const float* src = feats + (base + row) * 64 + ch * 8;
        float4 a = *(const float4*)src;
        float4 b = *(const float4*)(src + 4);
        bf16x8 v;
        v[0] = (bf16)a.x; v[1] = (bf16)a.y; v[2] = (bf16)a.z; v[3] = (bf16)a.w;
        v[4] = (bf16)b.x; v[5] = (bf16)b.y; v[6] = (bf16)b.z; v[7] = (bf16)b.w;
        *(bf16x8*)(R2 + swz<64>(row, ch * 8)) = v;
    }
    __syncthreads();

    // residual stream in regs: x2[tt][r] = x2[token tt*16+l15][ch w*16+q*4+r]
    f32x4 x2[4];

    // -------- stage 1: x2^T = w_pre^T . feats^T + b_pre ---------------------
    {
        f32x4 acc[4];
#pragma unroll
        for (int tt = 0; tt < 4; ++tt) acc[tt] = fzero;
#pragma unroll
        for (int ks = 0; ks < 2; ++ks) {
            bf16x8 afr = *(const bf16x8*)(wp + OFF_PRE + ((w * 2 + ks) * 64 + lane) * 8);
#pragma unroll
            for (int tt = 0; tt < 4; ++tt) {
                bf16x8 bfr = *(const bf16x8*)(R2 + swz<64>(tt * 16 + l15, ks * 32 + q * 8));
                acc[tt] = MFMA16(afr, bfr, acc[tt]);
            }
        }
        const f32x4 bias = *(const f32x4*)(b_pre + w * 16 + q * 4);
#pragma unroll
        for (int tt = 0; tt < 4; ++tt) {
#pragma unroll
            for (int r = 0; r < 4; ++r) x2[tt][r] = acc[tt][r] + bias[r];
            st4(R3 + swz<128>(tt * 16 + l15, w * 16 + q * 4), x2[tt]);
        }
    }
    __syncthreads();

    // -------- stage 2: n1 = LN(x2)*g1+b1 -> R1 ------------------------------
    ln_rows(R3, R1, g1, b1, tid);
    __syncthreads();

    // -------- stage 3: qkv^T = w_qkv^T . n1^T + b_qkv -----------------------
    // wave w: M-tile w (Q head w -> R2 row-major), 8+w (K head w -> R3
    // row-major), 16+w (V head w -> R4 transposed [ch][tok]).
    {
        bf16x8 B[4][4];
#pragma unroll
        for (int ks = 0; ks < 4; ++ks)
#pragma unroll
            for (int tt = 0; tt < 4; ++tt)
                B[ks][tt] = *(const bf16x8*)(R1 + swz<128>(tt * 16 + l15, ks * 32 + q * 8));
#pragma unroll
        for (int part = 0; part < 3; ++part) {
            const int mt = part * 8 + w;
            f32x4 acc[4];
#pragma unroll
            for (int tt = 0; tt < 4; ++tt) acc[tt] = fzero;
#pragma unroll
            for (int ks = 0; ks < 4; ++ks) {
                bf16x8 afr = *(const bf16x8*)(wp + OFF_QKV + ((mt * 4 + ks) * 64 + lane) * 8);
#pragma unroll
                for (int tt = 0; tt < 4; ++tt) acc[tt] = MFMA16(afr, B[ks][tt], acc[tt]);
            }
            const f32x4 bias = *(const f32x4*)(b_qkv + mt * 16 + q * 4);
            if (part == 0) {
#pragma unroll
                for (int tt = 0; tt < 4; ++tt)
                    st4(R2 + swz<128>(tt * 16 + l15, w * 16 + q * 4), acc[tt] + bias);
            } else if (part == 1) {
#pragma unroll
                for (int tt = 0; tt < 4; ++tt)
                    st4(R3 + swz<128>(tt * 16 + l15, w * 16 + q * 4), acc[tt] + bias);
            } else {
#pragma unroll
                for (int tt = 0; tt < 4; ++tt)
#pragma unroll
                    for (int r = 0; r < 4; ++r)
                        R4[w * 1024 + swz<64>(q * 4 + r, tt * 16 + l15)] =
                            (bf16)(acc[tt][r] + bias[r]);
            }
        }
    }
    __syncthreads();

    // -------- stage 4: attention (wave w = head w), S^T = K.Q^T -------------
    {
        const int colA = w * 16 + (q & 1) * 8;  // HD=16: quads>=2 zero-padded
        const bool hi = (q >= 2);
        const bf16x8 z8 = zero8();
        bf16x8 Kf[4];
#pragma unroll
        for (int kt = 0; kt < 4; ++kt) {
            bf16x8 t = *(const bf16x8*)(R3 + swz<128>(kt * 16 + l15, colA));
            Kf[kt] = hi ? z8 : t;
        }
#pragma unroll
        for (int qt = 0; qt < 4; ++qt) {
            bf16x8 t = *(const bf16x8*)(R2 + swz<128>(qt * 16 + l15, colA));
            bf16x8 Qf = hi ? z8 : t;
            f32x4 S[4];
#pragma unroll
            for (int kt = 0; kt < 4; ++kt) S[kt] = MFMA16(Kf[kt], Qf, fzero);
            // softmax over ktok (rows of S^T) for fixed qtok = qt*16+l15
            float P[4][4];
            float mx = -1e30f;
#pragma unroll
            for (int kt = 0; kt < 4; ++kt)
#pragma unroll
                for (int r = 0; r < 4; ++r) {
                    const float sv = S[kt][r] * 0.25f;  // HD^-0.5
                    P[kt][r] = sv;
                    mx = fmaxf(mx, sv);
                }
            mx = fmaxf(mx, __shfl_xor(mx, 16));
            mx = fmaxf(mx, __shfl_xor(mx, 32));
            float lsum = 0.f;
#pragma unroll
            for (int kt = 0; kt < 4; ++kt)
#pragma unroll
                for (int r = 0; r < 4; ++r) {
                    const float e = __builtin_amdgcn_exp2f((P[kt][r] - mx) * 1.4426950408889634f);
                    P[kt][r] = e;
                    lsum += e;
                }
            lsum += __shfl_xor(lsum, 16);
            lsum += __shfl_xor(lsum, 32);
            const float inv = __builtin_amdgcn_rcpf(lsum);
#pragma unroll
            for (int kt = 0; kt < 4; ++kt)
#pragma unroll
                for (int r = 0; r < 4; ++r) P[kt][r] *= inv;
            // O^T = V^T . P^T ; P^T B-frags built in-register via shuffles
            f32x4 O = fzero;
#pragma unroll
            for (int ks = 0; ks < 2; ++ks) {
                bf16x8 Bf;
#pragma unroll
                for (int j = 0; j < 8; ++j) {
                    const int src = (((q & 1) * 2 + (j >> 2)) << 4) + l15;
                    const float v0 = __shfl(P[ks * 2][j & 3], src);
                    const float v1 = __shfl(P[ks * 2 + 1][j & 3], src);
                    Bf[j] = (bf16)((q >> 1) ? v1 : v0);
                }
                bf16x8 Af = *(const bf16x8*)(R4 + w * 1024 + swz<64>(l15, ks * 32 + q * 8));
                O = MFMA16(Af, Bf, O);
            }
            st4(R1 + swz<128>(qt * 16 + l15, w * 16 + q * 4), O);
        }
    }
    __syncthreads();

    // -------- stage 5: x2 += (O . w_proj)^T + b_proj; x2_bf16 -> R3 ---------
    {
        f32x4 acc[4];
#pragma unroll
        for (int tt = 0; tt < 4; ++tt) acc[tt] = fzero;
#pragma unroll
        for (int ks = 0; ks < 4; ++ks) {
            bf16x8 afr = *(const bf16x8*)(wp + OFF_PROJ + ((w * 4 + ks) * 64 + lane) * 8);
#pragma unroll
            for (int tt = 0; tt < 4; ++tt) {
                bf16x8 bfr = *(const bf16x8*)(R1 + swz<128>(tt * 16 + l15, ks * 32 + q * 8));
                acc[tt] = MFMA16(afr, bfr, acc[tt]);
            }
        }
        const f32x4 bias = *(const f32x4*)(b_proj + w * 16 + q * 4);
#pragma unroll
        for (int tt = 0; tt < 4; ++tt) {
#pragma unroll
            for (int r = 0; r < 4; ++r) x2[tt][r] += acc[tt][r] + bias[r];
            st4(R3 + swz<128>(tt * 16 + l15, w * 16 + q * 4), x2[tt]);
        }
    }
    __syncthreads();

    // -------- stage 6: n2 = LN(x2)*g2+b2 -> R1 ------------------------------
    ln_rows(R3, R1, g2, b2, tid);
    __syncthreads();

    // -------- stage 7: hidden = gelu(w_m1^T . n2^T + b_m1) -> R34 (64x256) --
    {
        bf16x8 B[4][4];
#pragma unroll
        for (int ks = 0; ks < 4; ++ks)
#pragma unroll
            for (int tt = 0; tt < 4; ++tt)
                B[ks][tt] = *(const bf16x8*)(R1 + swz<128>(tt * 16 + l15, ks * 32 + q * 8));
#pragma unroll
        for (int half = 0; half < 2; ++half) {
            const int mt = w * 2 + half;
            f32x4 acc[4];
#pragma unroll
            for (int tt = 0; tt < 4; ++tt) acc[tt] = fzero;
#pragma unroll
            for (int ks = 0; ks < 4; ++ks) {
                bf16x8 afr = *(const bf16x8*)(wp + OFF_M1 + ((mt * 4 + ks) * 64 + lane) * 8);
#pragma unroll
                for (int tt = 0; tt < 4; ++tt) acc[tt] = MFMA16(afr, B[ks][tt], acc[tt]);
            }
            const f32x4 bias = *(const f32x4*)(b_m1 + mt * 16 + q * 4);
#pragma unroll
            for (int tt = 0; tt < 4; ++tt) {
                f32x4 gl;
#pragma unroll
                for (int r = 0; r < 4; ++r) gl[r] = gelu_f(acc[tt][r] + bias[r]);
                st4(R34 + swz<256>(tt * 16 + l15, mt * 16 + q * 4), gl);
            }
        }
    }
    __syncthreads();

    // -------- stage 8: x2 += (hidden . w_m2)^T + b_m2; x2_bf16 -> R1 --------
    {
        f32x4 acc[4];
#pragma unroll
        for (int tt = 0; tt < 4; ++tt) acc[tt] = fzero;
#pragma unroll
        for (int ks = 0; ks < 8; ++ks) {
            bf16x8 afr = *(const bf16x8*)(wp + OFF_M2 + ((w * 8 + ks) * 64 + lane) * 8);
#pragma unroll
            for (int tt = 0; tt < 4; ++tt) {
                bf16x8 bfr = *(const bf16x8*)(R34 + swz<256>(tt * 16 + l15, ks * 32 + q * 8));
                acc[tt] = MFMA16(afr, bfr, acc[tt]);
            }
        }
        const f32x4 bias = *(const f32x4*)(b_m2 + w * 16 + q * 4);
#pragma unroll
        for (int tt = 0; tt < 4; ++tt) {
#pragma unroll
            for (int r = 0; r < 4; ++r) x2[tt][r] += acc[tt][r] + bias[r];
            st4(R1 + swz<128>(tt * 16 + l15, w * 16 + q * 4), x2[tt]);
        }
    }
    __syncthreads();

    // -------- stage 9: out^T = w_post^T . x2^T + b_post (fp32, dwordx4) -----
    {
        const int ct  = w >> 1;        // out-channel tile 0..3
        const int tt0 = (w & 1) * 2;   // token tiles tt0, tt0+1
        f32x4 acc[2];
#pragma unroll
        for (int rr = 0; rr < 2; ++rr) acc[rr] = fzero;
#pragma unroll
        for (int ks = 0; ks < 4; ++ks) {
            bf16x8 afr = *(const bf16x8*)(wp + OFF_POST + ((ct * 4 + ks) * 64 + lane) * 8);
#pragma unroll
            for (int rr = 0; rr < 2; ++rr) {
                bf16x8 bfr = *(const bf16x8*)(R1 + swz<128>((tt0 + rr) * 16 + l15, ks * 32 + q * 8));
                acc[rr] = MFMA16(afr, bfr, acc[rr]);
            }
        }
        const f32x4 bias = *(const f32x4*)(b_post + ct * 16 + q * 4);
#pragma unroll
        for (int rr = 0; rr < 2; ++rr) {
            f32x4 v = acc[rr] + bias;
            *(f32x4*)(out + (base + (tt0 + rr) * 16 + l15) * 64 + ct * 16 + q * 4) = v;
        }
    }
}

extern "C" void kernel_launch(void* const* d_in, const int* in_sizes, int n_in,
                              void* d_out, int out_size, void* d_ws, size_t ws_size,
                              hipStream_t stream) {
    const float* feats  = (const float*)d_in[0];
    const float* w_pre  = (const float*)d_in[1];
    const float* b_pre  = (const float*)d_in[2];
    const float* g1     = (const float*)d_in[3];
    const float* b1     = (const float*)d_in[4];
    const float* w_qkv  = (const float*)d_in[5];
    const float* b_qkv  = (const float*)d_in[6];
    const float* w_proj = (const float*)d_in[7];
    const float* b_proj = (const float*)d_in[8];
    const float* g2     = (const float*)d_in[9];
    const float* b2     = (const float*)d_in[10];
    const float* w_m1   = (const float*)d_in[11];
    const float* b_m1   = (const float*)d_in[12];
    const float* w_m2   = (const float*)d_in[13];
    const float* b_m2   = (const float*)d_in[14];
    const float* w_post = (const float*)d_in[15];
    const float* b_post = (const float*)d_in[16];

    bf16* wp = (bf16*)d_ws;  // 288 KB of packed bf16 W^T A-fragments

    pack_all<<<288, 64, 0, stream>>>(w_pre, w_qkv, w_proj, w_m1, w_m2, w_post, wp);

    fused_block_kernel<<<8192, 512, 0, stream>>>(
        feats, wp, b_pre, g1, b1, b_qkv, b_proj, g2, b2, b_m1, b_m2, b_post,
        (float*)d_out);
}